// Round 3
// baseline (458.785 us; speedup 1.0000x reference)
//
#include <hip/hip_runtime.h>

// NetVLAD — round 5: barrier-free wave-independent phase1.
// B=32, N=4096, D=256, K=128, Dc=64.
//
// Phase1: grid 256 (8 blocks/batch, 512 rows), 512 thr (8 waves), 1 blk/CU.
//   Each wave owns 64 rows (4 iters x 16) and computes ALL 12 weight tiles
//   itself. Weights (8 Wa + 4 W1) live in LDS as B-frags (96 KB, read-only).
//   ZERO __syncthreads in the main loop — waves fully independent.
//   Softmax wave-local: 8 kt regs + shfl_xor(1,2,4,8) within quad.
//   U = assign^T·h accumulated in-register via zero-padded 16x16x32 MFMA:
//     C-layout of h/assign (lane(li,q) holds [row=q*4+r][col=li]) is placed at
//     contraction slot c=q*8+r (slots 4-7 zero) on BOTH operands -> contracts
//     exactly over the 16 rows. No LDS transpose, no shuffles.
//   Flush: block LDS tree-reduce (weights area dead) -> non-atomic per-block
//   partials in ws. No atomics, no memset.
// Phase2: per batch, sum 8 partials, vlad = U_tot@W2^T + mass*(b2-centroid)
//   in f32, L2-normalize.
//
// MFMA 16x16x32 layouts (m89/m120-verified):
//   A: lane holds A[m=lane&15][c=(lane>>4)*8+j]
//   B: lane holds B[c=(lane>>4)*8+j][n=lane&15]
//   C/D: lane holds D[row=(lane>>4)*4+r][col=lane&15]

#define B_   32
#define N_   4096
#define D_   256
#define K_   128
#define DC_  64
#define ITERS 4           // 16-row iters per wave (64 rows/wave, 512/block)
#define NEG  0.01f

typedef __attribute__((ext_vector_type(8))) short bf16x8;
typedef __attribute__((ext_vector_type(4))) float f32x4;

// LDS: 96 KB weight B-frags [g=0..11][ks=0..7][lane][16B]; flush reuses
// bytes 0..65535 (U reduce) + 65536..69631 (mass reduce).
#define LDS_BYTES 98304

__device__ __forceinline__ unsigned short f2bf(float x) {
  union { float f; unsigned u; } v; v.f = x;
  unsigned r = v.u + 0x7fffu + ((v.u >> 16) & 1u);
  return (unsigned short)(r >> 16);
}
__device__ __forceinline__ unsigned pack2(float a, float b) {
  return (unsigned)f2bf(a) | ((unsigned)f2bf(b) << 16);
}
__device__ __forceinline__ bf16x8 ldf(const char* s, int off) {
  return *reinterpret_cast<const bf16x8*>(s + off);
}
__device__ __forceinline__ bf16x8 fragz(unsigned lo, unsigned hi) {
  union { unsigned u[4]; bf16x8 v; } t;
  t.u[0] = lo; t.u[1] = hi; t.u[2] = 0u; t.u[3] = 0u;
  return t.v;
}
__device__ __forceinline__ bf16x8 pack8(float4 a, float4 c) {
  union { unsigned u[4]; bf16x8 v; } t;
  t.u[0] = pack2(a.x, a.y); t.u[1] = pack2(a.z, a.w);
  t.u[2] = pack2(c.x, c.y); t.u[3] = pack2(c.z, c.w);
  return t.v;
}

__global__ __launch_bounds__(512, 2)
void netvlad_phase1(const float* __restrict__ desc, const float* __restrict__ W1,
                    const float* __restrict__ b1, const float* __restrict__ Wa,
                    const float* __restrict__ ba,
                    float* __restrict__ ws_u, float* __restrict__ ws_m)
{
  extern __shared__ char smem[];
  const int t    = threadIdx.x;
  const int b    = blockIdx.x >> 3;
  const int blk  = blockIdx.x & 7;
  const int w    = t >> 6;
  const int lane = t & 63;
  const int li   = lane & 15;
  const int q    = lane >> 4;

  // ---- weights -> LDS B-frags (the only cooperative phase) ----
  for (int p = t; p < 6144; p += 512) {
    int L = p & 63, ks = (p >> 6) & 7, g = p >> 9;   // g: 0..7 Wa, 8..11 W1
    const float* src = (g < 8 ? Wa + (size_t)(g * 16 + (L & 15)) * D_
                              : W1 + (size_t)((g - 8) * 16 + (L & 15)) * D_)
                       + ks * 32 + ((L >> 4) << 3);
    float4 a = *(const float4*)src, c = *(const float4*)(src + 4);
    uint4 o;
    o.x = pack2(a.x, a.y); o.y = pack2(a.z, a.w);
    o.z = pack2(c.x, c.y); o.w = pack2(c.z, c.w);
    *reinterpret_cast<uint4*>(smem + ((g * 8 + ks) * 64 + L) * 16) = o;
  }

  float bar[8], b1r[4];
  #pragma unroll
  for (int kt = 0; kt < 8; ++kt) bar[kt] = ba[kt * 16 + li];
  #pragma unroll
  for (int et = 0; et < 4; ++et) b1r[et] = b1[et * 16 + li];

  f32x4 uacc[4][8];                 // U^T[e=et*16+q*4+r][k=kt*16+li]
  #pragma unroll
  for (int et = 0; et < 4; ++et)
    #pragma unroll
    for (int kt = 0; kt < 8; ++kt) uacc[et][kt] = (f32x4){0.f, 0.f, 0.f, 0.f};
  float mreg[8] = {0.f, 0.f, 0.f, 0.f, 0.f, 0.f, 0.f, 0.f};

  __syncthreads();                  // weights staged; last barrier before flush

  const int rowb = blk * 512 + w * 64;
  for (int it = 0; it < ITERS; ++it) {
    // ---- X rows -> A-frags in regs (direct from global, per-wave rows) ----
    const float* xb = desc + ((size_t)b * N_ + rowb + it * 16 + li) * D_ + q * 8;
    bf16x8 xf[8];
    #pragma unroll
    for (int ks = 0; ks < 8; ++ks) {
      float4 a = *(const float4*)(xb + ks * 32);
      float4 c = *(const float4*)(xb + ks * 32 + 4);
      xf[ks] = pack8(a, c);
    }

    // ---- h = X @ W1^T + b1, LeakyReLU, pack (C-layout == A-frag content) ----
    f32x4 hh[4];
    #pragma unroll
    for (int et = 0; et < 4; ++et) hh[et] = (f32x4){0.f, 0.f, 0.f, 0.f};
    #pragma unroll
    for (int ks = 0; ks < 8; ++ks)
      #pragma unroll
      for (int et = 0; et < 4; ++et)
        hh[et] = __builtin_amdgcn_mfma_f32_16x16x32_bf16(
            xf[ks], ldf(smem, (((8 + et) * 8 + ks) * 64 + lane) * 16), hh[et], 0, 0, 0);
    uint2 hpk[4];
    #pragma unroll
    for (int et = 0; et < 4; ++et) {
      float v0 = hh[et][0] + b1r[et], v1 = hh[et][1] + b1r[et];
      float v2 = hh[et][2] + b1r[et], v3 = hh[et][3] + b1r[et];
      v0 = v0 >= 0.f ? v0 : NEG * v0;  v1 = v1 >= 0.f ? v1 : NEG * v1;
      v2 = v2 >= 0.f ? v2 : NEG * v2;  v3 = v3 >= 0.f ? v3 : NEG * v3;
      hpk[et].x = pack2(v0, v1); hpk[et].y = pack2(v2, v3);
    }

    // ---- logits = X @ Wa^T + ba ----
    f32x4 accL[8];
    #pragma unroll
    for (int kt = 0; kt < 8; ++kt) accL[kt] = (f32x4){0.f, 0.f, 0.f, 0.f};
    #pragma unroll
    for (int ks = 0; ks < 8; ++ks)
      #pragma unroll
      for (int kt = 0; kt < 8; ++kt)
        accL[kt] = __builtin_amdgcn_mfma_f32_16x16x32_bf16(
            xf[ks], ldf(smem, ((kt * 8 + ks) * 64 + lane) * 16), accL[kt], 0, 0, 0);
    #pragma unroll
    for (int kt = 0; kt < 8; ++kt) {
      accL[kt][0] += bar[kt]; accL[kt][1] += bar[kt];
      accL[kt][2] += bar[kt]; accL[kt][3] += bar[kt];
    }

    // ---- wave-local softmax per row (k lives in {kt regs} x {li lanes}) ----
    float inv4[4];
    #pragma unroll
    for (int r = 0; r < 4; ++r) {
      float m = accL[0][r];
      #pragma unroll
      for (int kt = 1; kt < 8; ++kt) m = fmaxf(m, accL[kt][r]);
      #pragma unroll
      for (int off = 1; off < 16; off <<= 1) m = fmaxf(m, __shfl_xor(m, off, 64));
      float s = 0.f;
      #pragma unroll
      for (int kt = 0; kt < 8; ++kt) {
        float e = __expf(accL[kt][r] - m); accL[kt][r] = e; s += e;
      }
      #pragma unroll
      for (int off = 1; off < 16; off <<= 1) s += __shfl_xor(s, off, 64);
      inv4[r] = 1.0f / s;
    }

    // ---- U += assign^T · h via zero-padded 16x16x32 (contract 16 rows) ----
    #pragma unroll
    for (int kt = 0; kt < 8; ++kt) {
      float a0 = accL[kt][0] * inv4[0], a1 = accL[kt][1] * inv4[1];
      float a2 = accL[kt][2] * inv4[2], a3 = accL[kt][3] * inv4[3];
      mreg[kt] += a0 + a1 + a2 + a3;
      bf16x8 af = fragz(pack2(a0, a1), pack2(a2, a3));
      #pragma unroll
      for (int et = 0; et < 4; ++et)
        uacc[et][kt] = __builtin_amdgcn_mfma_f32_16x16x32_bf16(
            fragz(hpk[et].x, hpk[et].y), af, uacc[et][kt], 0, 0, 0);
    }
  }

  // ---- mass: cross-quad reduce (rows live in quads) ----
  #pragma unroll
  for (int kt = 0; kt < 8; ++kt) {
    float v = mreg[kt];
    v += __shfl_xor(v, 16, 64);
    v += __shfl_xor(v, 32, 64);
    mreg[kt] = v;
  }

  // ---- flush: block tree-reduce in LDS (weights dead), plain stores ----
  const size_t obase = (size_t)(b * 8 + blk) * 4 * 2048;
  for (int et = 0; et < 4; ++et) {
    __syncthreads();   // round 0: all weight reads done; later: prev reads done
    #pragma unroll
    for (int kt = 0; kt < 8; ++kt)
      *reinterpret_cast<f32x4*>(smem + ((w * 8 + kt) * 64 + lane) * 16) = uacc[et][kt];
    if (et == 0 && lane < 16) {
      #pragma unroll
      for (int kt = 0; kt < 8; ++kt)
        *reinterpret_cast<float*>(smem + 65536 + (w * 128 + kt * 16 + lane) * 4) = mreg[kt];
    }
    __syncthreads();
    float4 s = {0.f, 0.f, 0.f, 0.f};
    #pragma unroll
    for (int p = 0; p < 8; ++p) {
      float4 v = *reinterpret_cast<const float4*>(smem + p * 8192 + t * 16);
      s.x += v.x; s.y += v.y; s.z += v.z; s.w += v.w;
    }
    *reinterpret_cast<float4*>(ws_u + obase + et * 2048 + t * 4) = s;
    if (et == 0 && t < 128) {
      float sm = 0.f;
      #pragma unroll
      for (int p = 0; p < 8; ++p)
        sm += *reinterpret_cast<const float*>(smem + 65536 + (p * 128 + t) * 4);
      ws_m[(b * 8 + blk) * 128 + t] = sm;
    }
  }
}

__global__ __launch_bounds__(1024)
void netvlad_phase2(const float* __restrict__ ws_u, const float* __restrict__ ws_m,
                    const float* __restrict__ W2, const float* __restrict__ b2,
                    const float* __restrict__ centroid, float* __restrict__ out)
{
  __shared__ float u[DC_ * K_];      // [e][k]  32 KB
  __shared__ float w2t[DC_ * DC_];   // [e][d]  16 KB
  __shared__ float msh[K_];
  __shared__ float red[17];
  const int b = blockIdx.x, t = threadIdx.x;

  // sum 8 block-partials; decode frag layout -> [e][k]
  for (int idx = t; idx < 8192; idx += 1024) {
    int et = idx >> 11, j = idx & 2047;
    int kt = j >> 8, ln = (j >> 2) & 63, r = j & 3;
    int e = et * 16 + (ln >> 4) * 4 + r, k = kt * 16 + (ln & 15);
    float s = 0.f;
    #pragma unroll
    for (int p = 0; p < 8; ++p)
      s += ws_u[((size_t)(b * 8 + p) * 4 + et) * 2048 + j];
    u[e * K_ + k] = s;
  }
  for (int idx = t; idx < DC_ * DC_; idx += 1024)
    w2t[(idx & 63) * 64 + (idx >> 6)] = W2[idx];   // w2t[e][d] = W2[d][e]
  if (t < K_) {
    float s = 0.f;
    #pragma unroll
    for (int p = 0; p < 8; ++p) s += ws_m[(b * 8 + p) * 128 + t];
    msh[t] = s;
  }
  __syncthreads();

  // vlad[k][d0..d0+7] = sum_e u[e][k]*W2[d][e] + mass[k]*(b2[d]-centroid[k][d])
  const int k = t >> 3, d0 = (t & 7) * 8;
  float acc[8] = {0.f, 0.f, 0.f, 0.f, 0.f, 0.f, 0.f, 0.f};
  #pragma unroll 8
  for (int e = 0; e < DC_; ++e) {
    float uk = u[e * K_ + k];
    float4 wa = *(const float4*)&w2t[e * 64 + d0];
    float4 wb = *(const float4*)&w2t[e * 64 + d0 + 4];
    acc[0] += uk * wa.x; acc[1] += uk * wa.y; acc[2] += uk * wa.z; acc[3] += uk * wa.w;
    acc[4] += uk * wb.x; acc[5] += uk * wb.y; acc[6] += uk * wb.z; acc[7] += uk * wb.w;
  }
  const float mk = msh[k];
  const float* cb = centroid + k * 64 + d0;
  const float* bb = b2 + d0;
  #pragma unroll
  for (int j = 0; j < 8; ++j) acc[j] += mk * (bb[j] - cb[j]);

  float ss = 0.f;
  #pragma unroll
  for (int j = 0; j < 8; ++j) ss += acc[j] * acc[j];
  #pragma unroll
  for (int off = 32; off > 0; off >>= 1) ss += __shfl_down(ss, off, 64);
  if ((t & 63) == 0) red[t >> 6] = ss;
  __syncthreads();
  if (t == 0) {
    float s = 0.f;
    #pragma unroll
    for (int i = 0; i < 16; ++i) s += red[i];
    red[16] = 1.0f / fmaxf(sqrtf(s), 1e-12f);
  }
  __syncthreads();
  const float inv = red[16];
  float* op = out + (size_t)b * (K_ * DC_) + k * 64 + d0;
  float4 o0 = {acc[0] * inv, acc[1] * inv, acc[2] * inv, acc[3] * inv};
  float4 o1 = {acc[4] * inv, acc[5] * inv, acc[6] * inv, acc[7] * inv};
  *reinterpret_cast<float4*>(op)     = o0;
  *reinterpret_cast<float4*>(op + 4) = o1;
}

extern "C" void kernel_launch(void* const* d_in, const int* in_sizes, int n_in,
                              void* d_out, int out_size, void* d_ws, size_t ws_size,
                              hipStream_t stream) {
  const float* desc     = (const float*)d_in[0];
  const float* W1       = (const float*)d_in[1];
  const float* b1       = (const float*)d_in[2];
  const float* W2       = (const float*)d_in[3];
  const float* b2       = (const float*)d_in[4];
  const float* Wa       = (const float*)d_in[5];
  const float* ba       = (const float*)d_in[6];
  const float* centroid = (const float*)d_in[7];
  float* out = (float*)d_out;

  float* ws_u = (float*)d_ws;                      // 256 blocks x 8192 f32 = 8 MB
  float* ws_m = ws_u + (size_t)B_ * 8 * 4 * 2048;  // 256 x 128 f32 = 128 KB

  hipFuncSetAttribute(reinterpret_cast<const void*>(netvlad_phase1),
                      hipFuncAttributeMaxDynamicSharedMemorySize, LDS_BYTES);

  netvlad_phase1<<<dim3(B_ * 8), dim3(512), LDS_BYTES, stream>>>(
      desc, W1, b1, Wa, ba, ws_u, ws_m);
  netvlad_phase2<<<dim3(B_), dim3(1024), 0, stream>>>(
      ws_u, ws_m, W2, b2, centroid, out);
}

// Round 4
// 444.883 us; speedup vs baseline: 1.0312x; 1.0312x over previous
//
#include <hip/hip_runtime.h>

// NetVLAD — round 6: round-5 design + scratch-spill fix.
// B=32, N=4096, D=256, K=128, Dc=64.
//
// ROUND-5 BUG: the flush loop over `et` lacked #pragma unroll; LLVM kept it
// rolled, so uacc[et][kt] was runtime-indexed -> the ENTIRE 128-VGPR uacc
// array was demoted to scratch (rule #20). Every main-loop MFMA round-tripped
// its accumulator through HBM-backed scratch: 443 MB fetch / 198 MB write,
// MfmaUtil 2%, VGPR_Count 128 (uacc not in regs). Fix: force full unroll so
// every uacc access is compile-time-indexed.
//
// Phase1: grid 256 (8 blocks/batch, 512 rows), 512 thr (8 waves), 1 blk/CU.
//   Each wave owns 64 rows (4 iters x 16) and computes ALL 12 weight tiles
//   itself. Weights (8 Wa + 4 W1) live in LDS as B-frags (96 KB, read-only).
//   ZERO __syncthreads in the main loop — waves fully independent.
//   Softmax wave-local: 8 kt regs + shfl_xor(1,2,4,8) within quad.
//   U = assign^T·h accumulated in-register via zero-padded 16x16x32 MFMA:
//     C-layout of h/assign (lane(li,q) holds [row=q*4+r][col=li]) is placed at
//     contraction slot c=q*8+r (slots 4-7 zero) on BOTH operands -> contracts
//     exactly over the 16 rows. No LDS transpose, no shuffles.
//   Flush: block LDS tree-reduce (weights area dead) -> non-atomic per-block
//   partials in ws. No atomics, no memset.
// Phase2: per batch, sum 8 partials, vlad = U_tot@W2^T + mass*(b2-centroid)
//   in f32, L2-normalize.
//
// MFMA 16x16x32 layouts (m89/m120-verified):
//   A: lane holds A[m=lane&15][c=(lane>>4)*8+j]
//   B: lane holds B[c=(lane>>4)*8+j][n=lane&15]
//   C/D: lane holds D[row=(lane>>4)*4+r][col=lane&15]

#define B_   32
#define N_   4096
#define D_   256
#define K_   128
#define DC_  64
#define ITERS 4           // 16-row iters per wave (64 rows/wave, 512/block)
#define NEG  0.01f

typedef __attribute__((ext_vector_type(8))) short bf16x8;
typedef __attribute__((ext_vector_type(4))) float f32x4;

// LDS: 96 KB weight B-frags [g=0..11][ks=0..7][lane][16B]; flush reuses
// bytes 0..65535 (U reduce) + 65536..69631 (mass reduce).
#define LDS_BYTES 98304

__device__ __forceinline__ unsigned short f2bf(float x) {
  union { float f; unsigned u; } v; v.f = x;
  unsigned r = v.u + 0x7fffu + ((v.u >> 16) & 1u);
  return (unsigned short)(r >> 16);
}
__device__ __forceinline__ unsigned pack2(float a, float b) {
  return (unsigned)f2bf(a) | ((unsigned)f2bf(b) << 16);
}
__device__ __forceinline__ bf16x8 ldf(const char* s, int off) {
  return *reinterpret_cast<const bf16x8*>(s + off);
}
__device__ __forceinline__ bf16x8 fragz(unsigned lo, unsigned hi) {
  union { unsigned u[4]; bf16x8 v; } t;
  t.u[0] = lo; t.u[1] = hi; t.u[2] = 0u; t.u[3] = 0u;
  return t.v;
}
__device__ __forceinline__ bf16x8 pack8(float4 a, float4 c) {
  union { unsigned u[4]; bf16x8 v; } t;
  t.u[0] = pack2(a.x, a.y); t.u[1] = pack2(a.z, a.w);
  t.u[2] = pack2(c.x, c.y); t.u[3] = pack2(c.z, c.w);
  return t.v;
}

__global__ __launch_bounds__(512, 2)
void netvlad_phase1(const float* __restrict__ desc, const float* __restrict__ W1,
                    const float* __restrict__ b1, const float* __restrict__ Wa,
                    const float* __restrict__ ba,
                    float* __restrict__ ws_u, float* __restrict__ ws_m)
{
  extern __shared__ char smem[];
  const int t    = threadIdx.x;
  const int b    = blockIdx.x >> 3;
  const int blk  = blockIdx.x & 7;
  const int w    = t >> 6;
  const int lane = t & 63;
  const int li   = lane & 15;
  const int q    = lane >> 4;

  // ---- weights -> LDS B-frags (the only cooperative phase) ----
  for (int p = t; p < 6144; p += 512) {
    int L = p & 63, ks = (p >> 6) & 7, g = p >> 9;   // g: 0..7 Wa, 8..11 W1
    const float* src = (g < 8 ? Wa + (size_t)(g * 16 + (L & 15)) * D_
                              : W1 + (size_t)((g - 8) * 16 + (L & 15)) * D_)
                       + ks * 32 + ((L >> 4) << 3);
    float4 a = *(const float4*)src, c = *(const float4*)(src + 4);
    uint4 o;
    o.x = pack2(a.x, a.y); o.y = pack2(a.z, a.w);
    o.z = pack2(c.x, c.y); o.w = pack2(c.z, c.w);
    *reinterpret_cast<uint4*>(smem + ((g * 8 + ks) * 64 + L) * 16) = o;
  }

  float bar[8], b1r[4];
  #pragma unroll
  for (int kt = 0; kt < 8; ++kt) bar[kt] = ba[kt * 16 + li];
  #pragma unroll
  for (int et = 0; et < 4; ++et) b1r[et] = b1[et * 16 + li];

  f32x4 uacc[4][8];                 // U^T[e=et*16+q*4+r][k=kt*16+li]
  #pragma unroll
  for (int et = 0; et < 4; ++et)
    #pragma unroll
    for (int kt = 0; kt < 8; ++kt) uacc[et][kt] = (f32x4){0.f, 0.f, 0.f, 0.f};
  float mreg[8] = {0.f, 0.f, 0.f, 0.f, 0.f, 0.f, 0.f, 0.f};

  __syncthreads();                  // weights staged; last barrier before flush

  const int rowb = blk * 512 + w * 64;
  for (int it = 0; it < ITERS; ++it) {
    // ---- X rows -> A-frags in regs (direct from global, per-wave rows) ----
    const float* xb = desc + ((size_t)b * N_ + rowb + it * 16 + li) * D_ + q * 8;
    bf16x8 xf[8];
    #pragma unroll
    for (int ks = 0; ks < 8; ++ks) {
      float4 a = *(const float4*)(xb + ks * 32);
      float4 c = *(const float4*)(xb + ks * 32 + 4);
      xf[ks] = pack8(a, c);
    }

    // ---- h = X @ W1^T + b1, LeakyReLU, pack (C-layout == A-frag content) ----
    f32x4 hh[4];
    #pragma unroll
    for (int et = 0; et < 4; ++et) hh[et] = (f32x4){0.f, 0.f, 0.f, 0.f};
    #pragma unroll
    for (int ks = 0; ks < 8; ++ks)
      #pragma unroll
      for (int et = 0; et < 4; ++et)
        hh[et] = __builtin_amdgcn_mfma_f32_16x16x32_bf16(
            xf[ks], ldf(smem, (((8 + et) * 8 + ks) * 64 + lane) * 16), hh[et], 0, 0, 0);
    uint2 hpk[4];
    #pragma unroll
    for (int et = 0; et < 4; ++et) {
      float v0 = hh[et][0] + b1r[et], v1 = hh[et][1] + b1r[et];
      float v2 = hh[et][2] + b1r[et], v3 = hh[et][3] + b1r[et];
      v0 = v0 >= 0.f ? v0 : NEG * v0;  v1 = v1 >= 0.f ? v1 : NEG * v1;
      v2 = v2 >= 0.f ? v2 : NEG * v2;  v3 = v3 >= 0.f ? v3 : NEG * v3;
      hpk[et].x = pack2(v0, v1); hpk[et].y = pack2(v2, v3);
    }

    // ---- logits = X @ Wa^T + ba ----
    f32x4 accL[8];
    #pragma unroll
    for (int kt = 0; kt < 8; ++kt) accL[kt] = (f32x4){0.f, 0.f, 0.f, 0.f};
    #pragma unroll
    for (int ks = 0; ks < 8; ++ks)
      #pragma unroll
      for (int kt = 0; kt < 8; ++kt)
        accL[kt] = __builtin_amdgcn_mfma_f32_16x16x32_bf16(
            xf[ks], ldf(smem, ((kt * 8 + ks) * 64 + lane) * 16), accL[kt], 0, 0, 0);
    #pragma unroll
    for (int kt = 0; kt < 8; ++kt) {
      accL[kt][0] += bar[kt]; accL[kt][1] += bar[kt];
      accL[kt][2] += bar[kt]; accL[kt][3] += bar[kt];
    }

    // ---- wave-local softmax per row (k lives in {kt regs} x {li lanes}) ----
    float inv4[4];
    #pragma unroll
    for (int r = 0; r < 4; ++r) {
      float m = accL[0][r];
      #pragma unroll
      for (int kt = 1; kt < 8; ++kt) m = fmaxf(m, accL[kt][r]);
      #pragma unroll
      for (int off = 1; off < 16; off <<= 1) m = fmaxf(m, __shfl_xor(m, off, 64));
      float s = 0.f;
      #pragma unroll
      for (int kt = 0; kt < 8; ++kt) {
        float e = __expf(accL[kt][r] - m); accL[kt][r] = e; s += e;
      }
      #pragma unroll
      for (int off = 1; off < 16; off <<= 1) s += __shfl_xor(s, off, 64);
      inv4[r] = 1.0f / s;
    }

    // ---- U += assign^T · h via zero-padded 16x16x32 (contract 16 rows) ----
    #pragma unroll
    for (int kt = 0; kt < 8; ++kt) {
      float a0 = accL[kt][0] * inv4[0], a1 = accL[kt][1] * inv4[1];
      float a2 = accL[kt][2] * inv4[2], a3 = accL[kt][3] * inv4[3];
      mreg[kt] += a0 + a1 + a2 + a3;
      bf16x8 af = fragz(pack2(a0, a1), pack2(a2, a3));
      #pragma unroll
      for (int et = 0; et < 4; ++et)
        uacc[et][kt] = __builtin_amdgcn_mfma_f32_16x16x32_bf16(
            fragz(hpk[et].x, hpk[et].y), af, uacc[et][kt], 0, 0, 0);
    }
  }

  // ---- mass: cross-quad reduce (rows live in quads) ----
  #pragma unroll
  for (int kt = 0; kt < 8; ++kt) {
    float v = mreg[kt];
    v += __shfl_xor(v, 16, 64);
    v += __shfl_xor(v, 32, 64);
    mreg[kt] = v;
  }

  // ---- flush: block tree-reduce in LDS (weights dead), plain stores ----
  // #pragma unroll is LOAD-BEARING: a rolled loop makes uacc[et] runtime-
  // indexed -> whole uacc array demoted to scratch for the entire kernel
  // (rule #20; this was round-5's 500 MB / 2%-MfmaUtil bug).
  const size_t obase = (size_t)(b * 8 + blk) * 4 * 2048;
  #pragma unroll
  for (int et = 0; et < 4; ++et) {
    __syncthreads();   // round 0: all weight reads done; later: prev reads done
    #pragma unroll
    for (int kt = 0; kt < 8; ++kt)
      *reinterpret_cast<f32x4*>(smem + ((w * 8 + kt) * 64 + lane) * 16) = uacc[et][kt];
    if (et == 0 && lane < 16) {
      #pragma unroll
      for (int kt = 0; kt < 8; ++kt)
        *reinterpret_cast<float*>(smem + 65536 + (w * 128 + kt * 16 + lane) * 4) = mreg[kt];
    }
    __syncthreads();
    float4 s = {0.f, 0.f, 0.f, 0.f};
    #pragma unroll
    for (int p = 0; p < 8; ++p) {
      float4 v = *reinterpret_cast<const float4*>(smem + p * 8192 + t * 16);
      s.x += v.x; s.y += v.y; s.z += v.z; s.w += v.w;
    }
    *reinterpret_cast<float4*>(ws_u + obase + et * 2048 + t * 4) = s;
    if (et == 0 && t < 128) {
      float sm = 0.f;
      #pragma unroll
      for (int p = 0; p < 8; ++p)
        sm += *reinterpret_cast<const float*>(smem + 65536 + (p * 128 + t) * 4);
      ws_m[(b * 8 + blk) * 128 + t] = sm;
    }
  }
}

__global__ __launch_bounds__(1024)
void netvlad_phase2(const float* __restrict__ ws_u, const float* __restrict__ ws_m,
                    const float* __restrict__ W2, const float* __restrict__ b2,
                    const float* __restrict__ centroid, float* __restrict__ out)
{
  __shared__ float u[DC_ * K_];      // [e][k]  32 KB
  __shared__ float w2t[DC_ * DC_];   // [e][d]  16 KB
  __shared__ float msh[K_];
  __shared__ float red[17];
  const int b = blockIdx.x, t = threadIdx.x;

  // sum 8 block-partials; decode frag layout -> [e][k]
  for (int idx = t; idx < 8192; idx += 1024) {
    int et = idx >> 11, j = idx & 2047;
    int kt = j >> 8, ln = (j >> 2) & 63, r = j & 3;
    int e = et * 16 + (ln >> 4) * 4 + r, k = kt * 16 + (ln & 15);
    float s = 0.f;
    #pragma unroll
    for (int p = 0; p < 8; ++p)
      s += ws_u[((size_t)(b * 8 + p) * 4 + et) * 2048 + j];
    u[e * K_ + k] = s;
  }
  for (int idx = t; idx < DC_ * DC_; idx += 1024)
    w2t[(idx & 63) * 64 + (idx >> 6)] = W2[idx];   // w2t[e][d] = W2[d][e]
  if (t < K_) {
    float s = 0.f;
    #pragma unroll
    for (int p = 0; p < 8; ++p) s += ws_m[(b * 8 + p) * 128 + t];
    msh[t] = s;
  }
  __syncthreads();

  // vlad[k][d0..d0+7] = sum_e u[e][k]*W2[d][e] + mass[k]*(b2[d]-centroid[k][d])
  const int k = t >> 3, d0 = (t & 7) * 8;
  float acc[8] = {0.f, 0.f, 0.f, 0.f, 0.f, 0.f, 0.f, 0.f};
  #pragma unroll 8
  for (int e = 0; e < DC_; ++e) {
    float uk = u[e * K_ + k];
    float4 wa = *(const float4*)&w2t[e * 64 + d0];
    float4 wb = *(const float4*)&w2t[e * 64 + d0 + 4];
    acc[0] += uk * wa.x; acc[1] += uk * wa.y; acc[2] += uk * wa.z; acc[3] += uk * wa.w;
    acc[4] += uk * wb.x; acc[5] += uk * wb.y; acc[6] += uk * wb.z; acc[7] += uk * wb.w;
  }
  const float mk = msh[k];
  const float* cb = centroid + k * 64 + d0;
  const float* bb = b2 + d0;
  #pragma unroll
  for (int j = 0; j < 8; ++j) acc[j] += mk * (bb[j] - cb[j]);

  float ss = 0.f;
  #pragma unroll
  for (int j = 0; j < 8; ++j) ss += acc[j] * acc[j];
  #pragma unroll
  for (int off = 32; off > 0; off >>= 1) ss += __shfl_down(ss, off, 64);
  if ((t & 63) == 0) red[t >> 6] = ss;
  __syncthreads();
  if (t == 0) {
    float s = 0.f;
    #pragma unroll
    for (int i = 0; i < 16; ++i) s += red[i];
    red[16] = 1.0f / fmaxf(sqrtf(s), 1e-12f);
  }
  __syncthreads();
  const float inv = red[16];
  float* op = out + (size_t)b * (K_ * DC_) + k * 64 + d0;
  float4 o0 = {acc[0] * inv, acc[1] * inv, acc[2] * inv, acc[3] * inv};
  float4 o1 = {acc[4] * inv, acc[5] * inv, acc[6] * inv, acc[7] * inv};
  *reinterpret_cast<float4*>(op)     = o0;
  *reinterpret_cast<float4*>(op + 4) = o1;
}

extern "C" void kernel_launch(void* const* d_in, const int* in_sizes, int n_in,
                              void* d_out, int out_size, void* d_ws, size_t ws_size,
                              hipStream_t stream) {
  const float* desc     = (const float*)d_in[0];
  const float* W1       = (const float*)d_in[1];
  const float* b1       = (const float*)d_in[2];
  const float* W2       = (const float*)d_in[3];
  const float* b2       = (const float*)d_in[4];
  const float* Wa       = (const float*)d_in[5];
  const float* ba       = (const float*)d_in[6];
  const float* centroid = (const float*)d_in[7];
  float* out = (float*)d_out;

  float* ws_u = (float*)d_ws;                      // 256 blocks x 8192 f32 = 8 MB
  float* ws_m = ws_u + (size_t)B_ * 8 * 4 * 2048;  // 256 x 128 f32 = 128 KB

  hipFuncSetAttribute(reinterpret_cast<const void*>(netvlad_phase1),
                      hipFuncAttributeMaxDynamicSharedMemorySize, LDS_BYTES);

  netvlad_phase1<<<dim3(B_ * 8), dim3(512), LDS_BYTES, stream>>>(
      desc, W1, b1, Wa, ba, ws_u, ws_m);
  netvlad_phase2<<<dim3(B_), dim3(1024), 0, stream>>>(
      ws_u, ws_m, W2, b2, centroid, out);
}

// Round 5
// 302.849 us; speedup vs baseline: 1.5149x; 1.4690x over previous
//
#include <hip/hip_runtime.h>

// NetVLAD — round 7: spill elimination (256-thr / 512-VGPR cap + literal-index flush).
// B=32, N=4096, D=256, K=128, Dc=64.
//
// ROUNDS 5/6 BUG: identical 443MB-fetch/198MB-write/VGPR=128 signature = uacc
// scratch traffic. Two candidate causes, BOTH fixed here:
//  (a) flush loop over `et` contains __syncthreads(); clang may refuse to
//      unroll convergent loops -> uacc[et] runtime-indexed -> demoted (rule #20).
//      FIX: flush hand-unrolled via macros with LITERAL et/kt — no loop var
//      ever touches uacc.
//  (b) __launch_bounds__(512,2) forces 2 waves/SIMD -> 256-VGPR cap; design
//      needs ~240+ -> pressure spill. FIX: 256-thr blocks, launch_bounds(256,1)
//      -> 512-VGPR cap, demand ~300 fits with slack (1 wave/SIMD by design).
//
// Phase1: grid 256 (8 blocks/batch, 512 rows), 256 thr (4 waves), 1 blk/CU.
//   Each wave owns 128 rows (8 iters x 16) and computes ALL 12 weight tiles.
//   Weights (8 Wa + 4 W1) in LDS as B-frags (96 KB, read-only).
//   ZERO __syncthreads in the main loop — waves fully independent.
//   X prefetch: next iter's 16 float4 issued right after current pack; HBM
//   latency hides under the MFMA/LDS phase (no TLP at 1 wave/SIMD).
//   Softmax wave-local: 8 kt regs + shfl_xor(1,2,4,8) within quad.
//   U = assign^T·h in-register via zero-padded 16x16x32 MFMA (contraction
//   slot c=q*8+r on both operands, slots 4-7 zero -> contracts the 16 rows).
//   Flush: block LDS tree-reduce (weights area dead) -> per-block partials.
// Phase2: per batch, sum 8 partials, vlad = U_tot@W2^T + mass*(b2-centroid),
//   L2-normalize.
//
// MFMA 16x16x32 layouts (m89/m120-verified):
//   A: lane holds A[m=lane&15][c=(lane>>4)*8+j]
//   B: lane holds B[c=(lane>>4)*8+j][n=lane&15]
//   C/D: lane holds D[row=(lane>>4)*4+r][col=lane&15]

#define B_   32
#define N_   4096
#define D_   256
#define K_   128
#define DC_  64
#define ITERS 8           // 16-row iters per wave (128 rows/wave, 512/block)
#define NEG  0.01f

typedef __attribute__((ext_vector_type(8))) short bf16x8;
typedef __attribute__((ext_vector_type(4))) float f32x4;

// LDS: 96 KB weight B-frags [g=0..11][ks=0..7][lane][16B]; flush reuses
// bytes 0..32767 (U reduce, 4 waves x 8KB) + 65536..67583 (mass reduce).
#define LDS_BYTES 98304

__device__ __forceinline__ unsigned short f2bf(float x) {
  union { float f; unsigned u; } v; v.f = x;
  unsigned r = v.u + 0x7fffu + ((v.u >> 16) & 1u);
  return (unsigned short)(r >> 16);
}
__device__ __forceinline__ unsigned pack2(float a, float b) {
  return (unsigned)f2bf(a) | ((unsigned)f2bf(b) << 16);
}
__device__ __forceinline__ bf16x8 ldf(const char* s, int off) {
  return *reinterpret_cast<const bf16x8*>(s + off);
}
__device__ __forceinline__ bf16x8 fragz(unsigned lo, unsigned hi) {
  union { unsigned u[4]; bf16x8 v; } t;
  t.u[0] = lo; t.u[1] = hi; t.u[2] = 0u; t.u[3] = 0u;
  return t.v;
}
__device__ __forceinline__ bf16x8 pack8(float4 a, float4 c) {
  union { unsigned u[4]; bf16x8 v; } t;
  t.u[0] = pack2(a.x, a.y); t.u[1] = pack2(a.z, a.w);
  t.u[2] = pack2(c.x, c.y); t.u[3] = pack2(c.z, c.w);
  return t.v;
}

__global__ __launch_bounds__(256, 1)
void netvlad_phase1(const float* __restrict__ desc, const float* __restrict__ W1,
                    const float* __restrict__ b1, const float* __restrict__ Wa,
                    const float* __restrict__ ba,
                    float* __restrict__ ws_u, float* __restrict__ ws_m)
{
  extern __shared__ char smem[];
  const int t    = threadIdx.x;
  const int b    = blockIdx.x >> 3;
  const int blk  = blockIdx.x & 7;
  const int w    = t >> 6;         // wave 0..3
  const int lane = t & 63;
  const int li   = lane & 15;
  const int q    = lane >> 4;

  // ---- weights -> LDS B-frags (the only cooperative phase) ----
  for (int p = t; p < 6144; p += 256) {
    int L = p & 63, ks = (p >> 6) & 7, g = p >> 9;   // g: 0..7 Wa, 8..11 W1
    const float* src = (g < 8 ? Wa + (size_t)(g * 16 + (L & 15)) * D_
                              : W1 + (size_t)((g - 8) * 16 + (L & 15)) * D_)
                       + ks * 32 + ((L >> 4) << 3);
    float4 a = *(const float4*)src, c = *(const float4*)(src + 4);
    uint4 o;
    o.x = pack2(a.x, a.y); o.y = pack2(a.z, a.w);
    o.z = pack2(c.x, c.y); o.w = pack2(c.z, c.w);
    *reinterpret_cast<uint4*>(smem + ((g * 8 + ks) * 64 + L) * 16) = o;
  }

  float bar[8], b1r[4];
  #pragma unroll
  for (int kt = 0; kt < 8; ++kt) bar[kt] = ba[kt * 16 + li];
  #pragma unroll
  for (int et = 0; et < 4; ++et) b1r[et] = b1[et * 16 + li];

  f32x4 uacc[4][8];                 // U^T[e=et*16+q*4+r][k=kt*16+li]
  #pragma unroll
  for (int et = 0; et < 4; ++et)
    #pragma unroll
    for (int kt = 0; kt < 8; ++kt) uacc[et][kt] = (f32x4){0.f, 0.f, 0.f, 0.f};
  float mreg[8] = {0.f, 0.f, 0.f, 0.f, 0.f, 0.f, 0.f, 0.f};

  // ---- X prefetch pipeline: raw float4 regs for the NEXT iter ----
  const int rowb = blk * 512 + w * 128;
  float4 xp[16];
  auto issueX = [&](int itn) {
    const float* xb = desc + ((size_t)b * N_ + rowb + itn * 16 + li) * D_ + q * 8;
    #pragma unroll
    for (int ks = 0; ks < 8; ++ks) {
      xp[2 * ks]     = *(const float4*)(xb + ks * 32);
      xp[2 * ks + 1] = *(const float4*)(xb + ks * 32 + 4);
    }
  };
  issueX(0);

  __syncthreads();                  // weights staged; last barrier before flush

  for (int it = 0; it < ITERS; ++it) {
    // ---- pack raw X -> A-frags, then immediately issue next iter's loads ----
    bf16x8 xf[8];
    #pragma unroll
    for (int ks = 0; ks < 8; ++ks) xf[ks] = pack8(xp[2 * ks], xp[2 * ks + 1]);
    if (it + 1 < ITERS) issueX(it + 1);

    // ---- h = X @ W1^T + b1, LeakyReLU, pack (C-layout == A-frag content) ----
    f32x4 hh[4];
    #pragma unroll
    for (int et = 0; et < 4; ++et) hh[et] = (f32x4){0.f, 0.f, 0.f, 0.f};
    #pragma unroll
    for (int ks = 0; ks < 8; ++ks)
      #pragma unroll
      for (int et = 0; et < 4; ++et)
        hh[et] = __builtin_amdgcn_mfma_f32_16x16x32_bf16(
            xf[ks], ldf(smem, (((8 + et) * 8 + ks) * 64 + lane) * 16), hh[et], 0, 0, 0);
    uint2 hpk[4];
    #pragma unroll
    for (int et = 0; et < 4; ++et) {
      float v0 = hh[et][0] + b1r[et], v1 = hh[et][1] + b1r[et];
      float v2 = hh[et][2] + b1r[et], v3 = hh[et][3] + b1r[et];
      v0 = v0 >= 0.f ? v0 : NEG * v0;  v1 = v1 >= 0.f ? v1 : NEG * v1;
      v2 = v2 >= 0.f ? v2 : NEG * v2;  v3 = v3 >= 0.f ? v3 : NEG * v3;
      hpk[et].x = pack2(v0, v1); hpk[et].y = pack2(v2, v3);
    }

    // ---- logits = X @ Wa^T + ba ----
    f32x4 accL[8];
    #pragma unroll
    for (int kt = 0; kt < 8; ++kt) accL[kt] = (f32x4){0.f, 0.f, 0.f, 0.f};
    #pragma unroll
    for (int ks = 0; ks < 8; ++ks)
      #pragma unroll
      for (int kt = 0; kt < 8; ++kt)
        accL[kt] = __builtin_amdgcn_mfma_f32_16x16x32_bf16(
            xf[ks], ldf(smem, ((kt * 8 + ks) * 64 + lane) * 16), accL[kt], 0, 0, 0);
    #pragma unroll
    for (int kt = 0; kt < 8; ++kt) {
      accL[kt][0] += bar[kt]; accL[kt][1] += bar[kt];
      accL[kt][2] += bar[kt]; accL[kt][3] += bar[kt];
    }

    // ---- wave-local softmax per row (k lives in {kt regs} x {li lanes}) ----
    float inv4[4];
    #pragma unroll
    for (int r = 0; r < 4; ++r) {
      float m = accL[0][r];
      #pragma unroll
      for (int kt = 1; kt < 8; ++kt) m = fmaxf(m, accL[kt][r]);
      #pragma unroll
      for (int off = 1; off < 16; off <<= 1) m = fmaxf(m, __shfl_xor(m, off, 64));
      float s = 0.f;
      #pragma unroll
      for (int kt = 0; kt < 8; ++kt) {
        float e = __expf(accL[kt][r] - m); accL[kt][r] = e; s += e;
      }
      #pragma unroll
      for (int off = 1; off < 16; off <<= 1) s += __shfl_xor(s, off, 64);
      inv4[r] = 1.0f / s;
    }

    // ---- U += assign^T · h via zero-padded 16x16x32 (contract 16 rows) ----
    #pragma unroll
    for (int kt = 0; kt < 8; ++kt) {
      float a0 = accL[kt][0] * inv4[0], a1 = accL[kt][1] * inv4[1];
      float a2 = accL[kt][2] * inv4[2], a3 = accL[kt][3] * inv4[3];
      mreg[kt] += a0 + a1 + a2 + a3;
      bf16x8 af = fragz(pack2(a0, a1), pack2(a2, a3));
      #pragma unroll
      for (int et = 0; et < 4; ++et)
        uacc[et][kt] = __builtin_amdgcn_mfma_f32_16x16x32_bf16(
            fragz(hpk[et].x, hpk[et].y), af, uacc[et][kt], 0, 0, 0);
    }
  }

  // ---- mass: cross-quad reduce (rows live in quads) ----
  #pragma unroll
  for (int kt = 0; kt < 8; ++kt) {
    float v = mreg[kt];
    v += __shfl_xor(v, 16, 64);
    v += __shfl_xor(v, 32, 64);
    mreg[kt] = v;
  }

  // ---- flush: block tree-reduce in LDS, plain stores. HAND-UNROLLED with
  // literal et/kt so no loop variable EVER indexes uacc (rule #20 immunity;
  // the rounds-5/6 500MB-scratch bug). Inner loops index LDS/global only.
  const size_t obase = (size_t)(b * 8 + blk) * 4 * 2048;

#define UST(ET, KT) \
  *reinterpret_cast<f32x4*>(smem + ((w * 8 + KT) * 64 + lane) * 16) = uacc[ET][KT];
#define USTROW(ET) \
  UST(ET, 0) UST(ET, 1) UST(ET, 2) UST(ET, 3) UST(ET, 4) UST(ET, 5) UST(ET, 6) UST(ET, 7)
#define MST(KT) \
  *reinterpret_cast<float*>(smem + 65536 + (w * 128 + KT * 16 + lane) * 4) = mreg[KT];

#define FLUSH_ET(ET)                                                          \
  __syncthreads();                                                            \
  USTROW(ET)                                                                  \
  if (ET == 0 && lane < 16) {                                                 \
    MST(0) MST(1) MST(2) MST(3) MST(4) MST(5) MST(6) MST(7)                   \
  }                                                                           \
  __syncthreads();                                                            \
  {                                                                           \
    _Pragma("unroll")                                                         \
    for (int c = 0; c < 2; ++c) {                                             \
      const int idx = t + c * 256;                                            \
      float4 s = {0.f, 0.f, 0.f, 0.f};                                        \
      _Pragma("unroll")                                                       \
      for (int p = 0; p < 4; ++p) {                                           \
        float4 v = *reinterpret_cast<const float4*>(smem + p * 8192 + idx * 16); \
        s.x += v.x; s.y += v.y; s.z += v.z; s.w += v.w;                       \
      }                                                                       \
      *reinterpret_cast<float4*>(ws_u + obase + ET * 2048 + idx * 4) = s;     \
    }                                                                         \
    if (ET == 0 && t < 128) {                                                 \
      float sm = 0.f;                                                         \
      _Pragma("unroll")                                                       \
      for (int p = 0; p < 4; ++p)                                             \
        sm += *reinterpret_cast<const float*>(smem + 65536 + (p * 128 + t) * 4); \
      ws_m[(b * 8 + blk) * 128 + t] = sm;                                     \
    }                                                                         \
  }

  FLUSH_ET(0)
  FLUSH_ET(1)
  FLUSH_ET(2)
  FLUSH_ET(3)

#undef FLUSH_ET
#undef MST
#undef USTROW
#undef UST
}

__global__ __launch_bounds__(1024)
void netvlad_phase2(const float* __restrict__ ws_u, const float* __restrict__ ws_m,
                    const float* __restrict__ W2, const float* __restrict__ b2,
                    const float* __restrict__ centroid, float* __restrict__ out)
{
  __shared__ float u[DC_ * K_];      // [e][k]  32 KB
  __shared__ float w2t[DC_ * DC_];   // [e][d]  16 KB
  __shared__ float msh[K_];
  __shared__ float red[17];
  const int b = blockIdx.x, t = threadIdx.x;

  // sum 8 block-partials; decode frag layout -> [e][k]
  for (int idx = t; idx < 8192; idx += 1024) {
    int et = idx >> 11, j = idx & 2047;
    int kt = j >> 8, ln = (j >> 2) & 63, r = j & 3;
    int e = et * 16 + (ln >> 4) * 4 + r, k = kt * 16 + (ln & 15);
    float s = 0.f;
    #pragma unroll
    for (int p = 0; p < 8; ++p)
      s += ws_u[((size_t)(b * 8 + p) * 4 + et) * 2048 + j];
    u[e * K_ + k] = s;
  }
  for (int idx = t; idx < DC_ * DC_; idx += 1024)
    w2t[(idx & 63) * 64 + (idx >> 6)] = W2[idx];   // w2t[e][d] = W2[d][e]
  if (t < K_) {
    float s = 0.f;
    #pragma unroll
    for (int p = 0; p < 8; ++p) s += ws_m[(b * 8 + p) * 128 + t];
    msh[t] = s;
  }
  __syncthreads();

  // vlad[k][d0..d0+7] = sum_e u[e][k]*W2[d][e] + mass[k]*(b2[d]-centroid[k][d])
  const int k = t >> 3, d0 = (t & 7) * 8;
  float acc[8] = {0.f, 0.f, 0.f, 0.f, 0.f, 0.f, 0.f, 0.f};
  #pragma unroll 8
  for (int e = 0; e < DC_; ++e) {
    float uk = u[e * K_ + k];
    float4 wa = *(const float4*)&w2t[e * 64 + d0];
    float4 wb = *(const float4*)&w2t[e * 64 + d0 + 4];
    acc[0] += uk * wa.x; acc[1] += uk * wa.y; acc[2] += uk * wa.z; acc[3] += uk * wa.w;
    acc[4] += uk * wb.x; acc[5] += uk * wb.y; acc[6] += uk * wb.z; acc[7] += uk * wb.w;
  }
  const float mk = msh[k];
  const float* cb = centroid + k * 64 + d0;
  const float* bb = b2 + d0;
  #pragma unroll
  for (int j = 0; j < 8; ++j) acc[j] += mk * (bb[j] - cb[j]);

  float ss = 0.f;
  #pragma unroll
  for (int j = 0; j < 8; ++j) ss += acc[j] * acc[j];
  #pragma unroll
  for (int off = 32; off > 0; off >>= 1) ss += __shfl_down(ss, off, 64);
  if ((t & 63) == 0) red[t >> 6] = ss;
  __syncthreads();
  if (t == 0) {
    float s = 0.f;
    #pragma unroll
    for (int i = 0; i < 16; ++i) s += red[i];
    red[16] = 1.0f / fmaxf(sqrtf(s), 1e-12f);
  }
  __syncthreads();
  const float inv = red[16];
  float* op = out + (size_t)b * (K_ * DC_) + k * 64 + d0;
  float4 o0 = {acc[0] * inv, acc[1] * inv, acc[2] * inv, acc[3] * inv};
  float4 o1 = {acc[4] * inv, acc[5] * inv, acc[6] * inv, acc[7] * inv};
  *reinterpret_cast<float4*>(op)     = o0;
  *reinterpret_cast<float4*>(op + 4) = o1;
}

extern "C" void kernel_launch(void* const* d_in, const int* in_sizes, int n_in,
                              void* d_out, int out_size, void* d_ws, size_t ws_size,
                              hipStream_t stream) {
  const float* desc     = (const float*)d_in[0];
  const float* W1       = (const float*)d_in[1];
  const float* b1       = (const float*)d_in[2];
  const float* W2       = (const float*)d_in[3];
  const float* b2       = (const float*)d_in[4];
  const float* Wa       = (const float*)d_in[5];
  const float* ba       = (const float*)d_in[6];
  const float* centroid = (const float*)d_in[7];
  float* out = (float*)d_out;

  float* ws_u = (float*)d_ws;                      // 256 blocks x 8192 f32 = 8 MB
  float* ws_m = ws_u + (size_t)B_ * 8 * 4 * 2048;  // 256 x 128 f32 = 128 KB

  hipFuncSetAttribute(reinterpret_cast<const void*>(netvlad_phase1),
                      hipFuncAttributeMaxDynamicSharedMemorySize, LDS_BYTES);

  netvlad_phase1<<<dim3(B_ * 8), dim3(256), LDS_BYTES, stream>>>(
      desc, W1, b1, Wa, ba, ws_u, ws_m);
  netvlad_phase2<<<dim3(B_), dim3(1024), 0, stream>>>(
      ws_u, ws_m, W2, b2, centroid, out);
}